// Round 4
// baseline (348.746 us; speedup 1.0000x reference)
//
#include <hip/hip_runtime.h>
#include <hip/hip_bf16.h>

#define NPTS 262144
#define DIM  128
#define KC   20
#define MP   10
#define LNEPS 1e-5f
#define EPSI  0.05f
#define CCAP  65536

typedef _Float16 half8 __attribute__((ext_vector_type(8)));
typedef float f32x4 __attribute__((ext_vector_type(4)));

union H8U4 { half8 h; uint4 u; };

// workspace layout (float offsets)
#define WS_PN     0          // 25600 normalized protos f32
#define WS_PHI    25600      // 13312 floats (208x128 f16 hi)
#define WS_PLO    38912      // 13312 floats (f16 lo)
#define WS_F      52224      // 25600 f accumulator
#define WS_NCOUNT 77824      // 200
#define WS_CCNT   78024      // 8 (int counter + pad)
#define WS_UH     78032      // 600 u history (3 x 200)
#define WS_SK     78632      // 20
#define WS_BC     78652      // 20
#define WS_PSB    78672      // 40*1024 partials
#define WS_PR     119632     // 200*1024
#define WS_EXPV   324432     // N*12 (10 + 2 pad)
#define WS_CORR   3470160    // N
#define WS_CIDX   3732304    // 65536 ints
// total 3797840 floats = 14.5 MB

#define EPITCH 210   // epilogue LDS pitch (bank-friendly)

__device__ __forceinline__ half8 lds_h8(const uint4* p) {
    return *reinterpret_cast<const half8*>(p);
}

// ---- normalize prototypes, emit f32 + f16 hi/lo (rows 200..207 zero-padded)
__global__ __launch_bounds__(64) void k_norm_protos(
    const float* __restrict__ pr, float* __restrict__ pn,
    _Float16* __restrict__ phi, _Float16* __restrict__ plo)
{
    int j = blockIdx.x, l = threadIdx.x;
    if (j < 200) {
        float x0 = pr[(size_t)j*128 + l], x1 = pr[(size_t)j*128 + 64 + l];
        float ss = x0*x0 + x1*x1;
        #pragma unroll
        for (int off = 32; off > 0; off >>= 1) ss += __shfl_xor(ss, off);
        float dn = fmaxf(sqrtf(ss), 1e-12f);
        float y0 = x0/dn, y1 = x1/dn;
        pn[(size_t)j*128 + l]      = y0;
        pn[(size_t)j*128 + 64 + l] = y1;
        _Float16 h0 = (_Float16)y0, h1 = (_Float16)y1;
        phi[(size_t)j*128 + l]      = h0;
        phi[(size_t)j*128 + 64 + l] = h1;
        plo[(size_t)j*128 + l]      = (_Float16)(y0 - (float)h0);
        plo[(size_t)j*128 + 64 + l] = (_Float16)(y1 - (float)h1);
    } else {
        phi[(size_t)j*128 + l] = (_Float16)0.f;  phi[(size_t)j*128 + 64 + l] = (_Float16)0.f;
        plo[(size_t)j*128 + l] = (_Float16)0.f;  plo[(size_t)j*128 + 64 + l] = (_Float16)0.f;
    }
}

// ---- main fused kernel. Grid 256 blocks x 512 threads (8 waves). Each block:
//  stage B (full 208x128 f16 hi/lo) in LDS once, then 4 chunks of 256 points:
//  A per-lane direct global load in MFMA-fragment layout, LN via 4-lane shfl,
//  barrier-free MFMA GEMM, plog store, on-chip epilogue.
__global__ __launch_bounds__(512, 2) void k_main(
    const float* __restrict__ feat, const int* __restrict__ gt,
    const _Float16* __restrict__ phi, const _Float16* __restrict__ plo,
    const float* __restrict__ fg, const float* __restrict__ fb,
    const float* __restrict__ mg, const float* __restrict__ mb,
    float* __restrict__ out_seg, float* __restrict__ plog,
    float* __restrict__ expv, float* __restrict__ psb, float* __restrict__ corr,
    int* __restrict__ cidx, int* __restrict__ ccnt)
{
    __shared__ __align__(16) char lds[163584];
    uint4* bHi = (uint4*)lds;                       // 3328 uint4 = 53248 B
    uint4* bLo = (uint4*)(lds + 53248);             // 53248 B
    float* epi = (float*)(lds + 106496);            // 64*210*4 = 53760 B
    float* sumS = (float*)(lds + 160256);           // 256*4
    int*   gtS  = (int*)(lds + 161280);             // 256*4
    float* part = (float*)(lds + 162304);           // 320*4 = 1280 -> 163584

    const int t = threadIdx.x;
    const int w = t >> 6, lane = t & 63;
    const int l15 = lane & 15, l4 = lane >> 4;

    // ---- stage full B to LDS (swizzled slot = s ^ (row&15)), once per block
    {
        const uint4* phi4 = (const uint4*)phi;
        const uint4* plo4 = (const uint4*)plo;
        #pragma unroll
        for (int ii = 0; ii < 13; ++ii) {
            int idx = ii*512 + t;
            bool ishi = idx < 3328;
            int ridx = ishi ? idx : idx - 3328;
            int dst = (ridx & ~15) | ((ridx & 15) ^ ((ridx >> 4) & 15));
            uint4 vv = ishi ? phi4[ridx] : plo4[ridx];
            (ishi ? bHi : bLo)[dst] = vv;
        }
    }
    __syncthreads();

    const float4* gfeat = (const float4*)feat;

    for (int ch = 0; ch < 4; ++ch) {
        const int cid = ch*256 + blockIdx.x;     // chunk id 0..1023
        const int pbase = cid * 256;             // global point base

        // ---- A direct loads in fragment layout: row = pbase+w*32+mt*16+l15
        float4 A[2][4][2];
        #pragma unroll
        for (int mt = 0; mt < 2; ++mt) {
            size_t rb = (size_t)(pbase + w*32 + mt*16 + l15) * 32;
            #pragma unroll
            for (int kst = 0; kst < 4; ++kst)
                #pragma unroll
                for (int h = 0; h < 2; ++h)
                    A[mt][kst][h] = gfeat[rb + kst*8 + l4*2 + h];
        }
        float4 G[4][2], Bb[4][2];
        {
            const float4* fg4 = (const float4*)fg;
            const float4* fb4 = (const float4*)fb;
            #pragma unroll
            for (int kst = 0; kst < 4; ++kst)
                #pragma unroll
                for (int h = 0; h < 2; ++h) {
                    G[kst][h]  = fg4[kst*8 + l4*2 + h];
                    Bb[kst][h] = fb4[kst*8 + l4*2 + h];
                }
        }

        // ---- LN + l2n per mt (4-lane group reduce: lanes {l15, l15+16, +32, +48})
        half8 fah[2][4], fal[2][4];
        #pragma unroll
        for (int mt = 0; mt < 2; ++mt) {
            float s0 = 0.f;
            #pragma unroll
            for (int kst = 0; kst < 4; ++kst)
                #pragma unroll
                for (int h = 0; h < 2; ++h) {
                    float4 v = A[mt][kst][h];
                    s0 += v.x + v.y + v.z + v.w;
                }
            s0 += __shfl_xor(s0, 16); s0 += __shfl_xor(s0, 32);
            float mean = s0 * (1.f/128.f);
            float s1 = 0.f;
            #pragma unroll
            for (int kst = 0; kst < 4; ++kst)
                #pragma unroll
                for (int h = 0; h < 2; ++h) {
                    float4 v = A[mt][kst][h];
                    float a = v.x-mean, b = v.y-mean, c = v.z-mean, d = v.w-mean;
                    s1 += a*a + b*b + c*c + d*d;
                }
            s1 += __shfl_xor(s1, 16); s1 += __shfl_xor(s1, 32);
            float rstd = rsqrtf(s1 * (1.f/128.f) + LNEPS);
            float s2 = 0.f;
            #pragma unroll
            for (int kst = 0; kst < 4; ++kst)
                #pragma unroll
                for (int h = 0; h < 2; ++h) {
                    float4 v = A[mt][kst][h];
                    float4 g = G[kst][h], bb = Bb[kst][h];
                    v.x = (v.x-mean)*rstd*g.x + bb.x;
                    v.y = (v.y-mean)*rstd*g.y + bb.y;
                    v.z = (v.z-mean)*rstd*g.z + bb.z;
                    v.w = (v.w-mean)*rstd*g.w + bb.w;
                    A[mt][kst][h] = v;
                    s2 += v.x*v.x + v.y*v.y + v.z*v.z + v.w*v.w;
                }
            s2 += __shfl_xor(s2, 16); s2 += __shfl_xor(s2, 32);
            float rl2 = 1.f / fmaxf(sqrtf(s2), 1e-12f);
            #pragma unroll
            for (int kst = 0; kst < 4; ++kst) {
                float4 va = A[mt][kst][0], vb = A[mt][kst][1];
                va.x*=rl2; va.y*=rl2; va.z*=rl2; va.w*=rl2;
                vb.x*=rl2; vb.y*=rl2; vb.z*=rl2; vb.w*=rl2;
                H8U4 h, lo;
                h.h[0]=(_Float16)va.x; h.h[1]=(_Float16)va.y; h.h[2]=(_Float16)va.z; h.h[3]=(_Float16)va.w;
                h.h[4]=(_Float16)vb.x; h.h[5]=(_Float16)vb.y; h.h[6]=(_Float16)vb.z; h.h[7]=(_Float16)vb.w;
                lo.h[0]=(_Float16)(va.x-(float)h.h[0]); lo.h[1]=(_Float16)(va.y-(float)h.h[1]);
                lo.h[2]=(_Float16)(va.z-(float)h.h[2]); lo.h[3]=(_Float16)(va.w-(float)h.h[3]);
                lo.h[4]=(_Float16)(vb.x-(float)h.h[4]); lo.h[5]=(_Float16)(vb.y-(float)h.h[5]);
                lo.h[6]=(_Float16)(vb.z-(float)h.h[6]); lo.h[7]=(_Float16)(vb.w-(float)h.h[7]);
                fah[mt][kst] = h.h;
                fal[mt][kst] = lo.h;
            }
        }

        // ---- barrier-free MFMA GEMM (B stationary in LDS)
        f32x4 acc[2][13];
        #pragma unroll
        for (int mt = 0; mt < 2; ++mt)
            #pragma unroll
            for (int nt = 0; nt < 13; ++nt)
                acc[mt][nt] = (f32x4){0.f,0.f,0.f,0.f};

        #pragma unroll
        for (int nt = 0; nt < 13; ++nt) {
            const uint4* bH = bHi + (nt*16 + l15)*16;
            const uint4* bL = bLo + (nt*16 + l15)*16;
            #pragma unroll
            for (int kst = 0; kst < 4; ++kst) {
                int sl = (kst*4 + l4) ^ l15;
                half8 bh = lds_h8(bH + sl);
                half8 bl = lds_h8(bL + sl);
                acc[0][nt] = __builtin_amdgcn_mfma_f32_16x16x32_f16(fah[0][kst], bh, acc[0][nt], 0,0,0);
                acc[0][nt] = __builtin_amdgcn_mfma_f32_16x16x32_f16(fal[0][kst], bh, acc[0][nt], 0,0,0);
                acc[0][nt] = __builtin_amdgcn_mfma_f32_16x16x32_f16(fah[0][kst], bl, acc[0][nt], 0,0,0);
                acc[0][nt] = __builtin_amdgcn_mfma_f32_16x16x32_f16(fal[0][kst], bl, acc[0][nt], 0,0,0);
                acc[1][nt] = __builtin_amdgcn_mfma_f32_16x16x32_f16(fah[1][kst], bh, acc[1][nt], 0,0,0);
                acc[1][nt] = __builtin_amdgcn_mfma_f32_16x16x32_f16(fal[1][kst], bh, acc[1][nt], 0,0,0);
                acc[1][nt] = __builtin_amdgcn_mfma_f32_16x16x32_f16(fah[1][kst], bl, acc[1][nt], 0,0,0);
                acc[1][nt] = __builtin_amdgcn_mfma_f32_16x16x32_f16(fal[1][kst], bl, acc[1][nt], 0,0,0);
            }
        }

        // ---- plog stores straight from acc
        #pragma unroll
        for (int mt = 0; mt < 2; ++mt)
            #pragma unroll
            for (int nt = 0; nt < 13; ++nt)
                #pragma unroll
                for (int rr = 0; rr < 4; ++rr)
                    if (nt < 12 || l15 < 8)
                        plog[(size_t)(pbase + w*32 + mt*16 + l4*4 + rr)*200 + nt*16 + l15]
                            = acc[mt][nt][rr];

        // ---- epilogue: 4 sub-phases of 64 points via epi LDS
        #pragma unroll 1
        for (int s = 0; s < 4; ++s) {
            if ((w >> 1) == s) {
                int rbase = (w & 1)*32;
                #pragma unroll
                for (int mt = 0; mt < 2; ++mt)
                    #pragma unroll
                    for (int nt = 0; nt < 13; ++nt)
                        #pragma unroll
                        for (int rr = 0; rr < 4; ++rr)
                            epi[(rbase + mt*16 + l4*4 + rr)*EPITCH + nt*16 + l15]
                                = acc[mt][nt][rr];
            }
            __syncthreads();
            if (t < 256) {
                const int q = t >> 2, sub = t & 3;
                const int n = pbase + s*64 + q;
                float ml[5];
                #pragma unroll
                for (int kk = 0; kk < 5; ++kk) {
                    int k = sub*5 + kk;
                    float mx = epi[q*EPITCH + k*10];
                    #pragma unroll
                    for (int m = 1; m < 10; ++m) mx = fmaxf(mx, epi[q*EPITCH + k*10 + m]);
                    ml[kk] = mx;
                }
                float s0 = ml[0]+ml[1]+ml[2]+ml[3]+ml[4];
                s0 += __shfl_xor(s0,1); s0 += __shfl_xor(s0,2);
                float mean = s0 / 20.f;
                float s1 = 0.f;
                #pragma unroll
                for (int kk = 0; kk < 5; ++kk) { float d = ml[kk]-mean; s1 += d*d; }
                s1 += __shfl_xor(s1,1); s1 += __shfl_xor(s1,2);
                float rstd = rsqrtf(s1 / 20.f + LNEPS);
                float bv = -1e30f; int bk = 0;
                #pragma unroll
                for (int kk = 0; kk < 5; ++kk) {
                    int k = sub*5 + kk;
                    float y = (ml[kk]-mean)*rstd*mg[k] + mb[k];
                    out_seg[(size_t)n*20 + k] = y;
                    if (y > bv) { bv = y; bk = k; }
                }
                #pragma unroll
                for (int off = 1; off <= 2; off <<= 1) {   // first-max-wins merge
                    float ov = __shfl_xor(bv, off);
                    int   ok = __shfl_xor(bk, off);
                    if (ov > bv || (ov == bv && ok < bk)) { bv = ov; bk = ok; }
                }
                int g = gt[n];
                if (sub == 0) {
                    bool isc = (bk == g);
                    corr[n] = isc ? 1.f : 0.f;
                    if (isc) {
                        int slot = atomicAdd(ccnt, 1);
                        if (slot < CCAP) cidx[slot] = n;
                    }
                    float se = 0.f;
                    #pragma unroll
                    for (int m = 0; m < 10; ++m) {
                        float e = expf(epi[q*EPITCH + g*10 + m] / EPSI);
                        expv[(size_t)n*12 + m] = e;
                        se += e;
                    }
                    expv[(size_t)n*12 + 10] = 0.f;
                    expv[(size_t)n*12 + 11] = 0.f;
                    sumS[s*64 + q] = se;
                    gtS[s*64 + q] = g;
                }
            }
            __syncthreads();
        }
        // ---- per-chunk class partials (deterministic two-stage)
        if (t < 160) {
            int c = t >> 3, o = t & 7;
            float cnt = 0.f, sm = 0.f;
            #pragma unroll 4
            for (int i = o*32; i < o*32 + 32; ++i)
                if (gtS[i] == c) { cnt += 1.f; sm += sumS[i]; }
            part[t] = cnt; part[160 + t] = sm;
        }
        __syncthreads();
        if (t < 20) {
            float cnt = 0.f, sm = 0.f;
            #pragma unroll
            for (int o = 0; o < 8; ++o) { cnt += part[t*8+o]; sm += part[160 + t*8+o]; }
            psb[(size_t)t*1024 + cid]      = cnt;
            psb[(size_t)(20+t)*1024 + cid] = sm;
        }
        __syncthreads();
    }
}

// ---- reduce class partials -> Bc, sk (deterministic tree)
__global__ __launch_bounds__(256) void k_reduce_sB(
    const float* __restrict__ psb, float* __restrict__ sk, float* __restrict__ Bc)
{
    __shared__ float red[256];
    int t = threadIdx.x, rrow = blockIdx.x;
    float s = 0.f;
    #pragma unroll
    for (int i = 0; i < 4; ++i) s += psb[(size_t)rrow*1024 + i*256 + t];
    red[t] = s; __syncthreads();
    for (int off = 128; off > 0; off >>= 1) { if (t < off) red[t] += red[t+off]; __syncthreads(); }
    if (t == 0) { if (rrow < 20) Bc[rrow] = red[0]; else sk[rrow-20] = red[0]; }
}

// ---- sinkhorn row pass with fused v-chain (iter = 1,2,3)
__global__ __launch_bounds__(256) void k_row(int iter,
    const int* __restrict__ gt, const float* __restrict__ expv,
    const float* __restrict__ uh, const float* __restrict__ sk,
    const float* __restrict__ Bc, float* __restrict__ pr)
{
    __shared__ float prodS[256*10];
    __shared__ int gtS[256];
    int t = threadIdx.x, b = blockIdx.x;
    int n = b*256 + t;
    int g = gt[n];
    float e[10];
    {
        const float4* e4 = (const float4*)(expv + (size_t)n*12);
        float4 ea = e4[0], eb = e4[1], ec = e4[2];
        e[0]=ea.x; e[1]=ea.y; e[2]=ea.z; e[3]=ea.w;
        e[4]=eb.x; e[5]=eb.y; e[6]=eb.z; e[7]=eb.w;
        e[8]=ec.x; e[9]=ec.y;
    }
    float skg = sk[g];
    float v = (skg > 0.f) ? 1.f/skg : 1.f;
    float B = Bc[g];
    float Bs = (B > 0.f) ? B : 1.f;
    for (int c = 1; c < iter; ++c) {
        const float* uc = uh + (c-1)*200 + g*10;
        float sc = 0.f;
        #pragma unroll
        for (int m = 0; m < 10; ++m) sc += e[m]*uc[m];
        v = (sc > 0.f) ? 1.f/(Bs*sc) : v/Bs;
    }
    #pragma unroll
    for (int m = 0; m < 10; ++m) prodS[t*10+m] = e[m]*v;
    gtS[t] = g;
    __syncthreads();
    if (t < 200) {
        int kk = t / 10, mm = t % 10;
        float acc = 0.f;
        for (int i = 0; i < 256; ++i)
            if (gtS[i] == kk) acc += prodS[i*10+mm];
        pr[(size_t)t*1024 + b] = acc;
    }
}

// ---- row partials -> u_hist[iter] (faithful rs>0 guard), deterministic
__global__ __launch_bounds__(256) void k_reduce_u(int iter,
    const float* __restrict__ pr, float* __restrict__ uh)
{
    __shared__ float red[256];
    int t = threadIdx.x, j = blockIdx.x;
    float s = 0.f;
    #pragma unroll
    for (int i = 0; i < 4; ++i) s += pr[(size_t)j*1024 + i*256 + t];
    red[t] = s; __syncthreads();
    for (int off = 128; off > 0; off >>= 1) { if (t < off) red[t] += red[t+off]; __syncthreads(); }
    if (t == 0) {
        float S = red[0];
        float uprev = (iter == 1) ? 1.f : uh[(iter-2)*200 + j];
        uh[(iter-1)*200 + j] = (S > 0.f) ? 1.f/(10.f*S) : uprev*0.1f;
    }
}

// ---- per-point proto assignment: ptarget + ncount
__global__ __launch_bounds__(256) void k_assign(
    const int* __restrict__ gt, const float* __restrict__ expv,
    const float* __restrict__ u, const float* __restrict__ corr,
    float* __restrict__ ptarget, float* __restrict__ ncount)
{
    int n = blockIdx.x*256 + threadIdx.x;
    int g = gt[n];
    const float* uk = u + g*10;
    float bv = -1e30f; int idx = 0;
    #pragma unroll
    for (int m = 0; m < 10; ++m) {
        float pm = expv[(size_t)n*12 + m] * uk[m];
        if (pm > bv) { bv = pm; idx = m; }
    }
    ptarget[n] = (float)(idx + 10*g);
    if (corr[n] != 0.f) atomicAdd(&ncount[g*10+idx], 1.f);
}

// ---- f accumulation: one wave per correct point, recompute _c exactly (f32)
__global__ __launch_bounds__(256) void k_accum(
    const float* __restrict__ feat, const int* __restrict__ gt,
    const float* __restrict__ fg, const float* __restrict__ fb,
    const float* __restrict__ expv, const float* __restrict__ u,
    const int* __restrict__ cidx, const int* __restrict__ ccnt,
    float* __restrict__ facc)
{
    int wid = (blockIdx.x*256 + threadIdx.x) >> 6;
    int lane = threadIdx.x & 63;
    int cnt = *ccnt; if (cnt > CCAP) cnt = CCAP;
    for (int i = wid; i < cnt; i += 1024) {
        int n = cidx[i];
        float x0 = feat[(size_t)n*128 + lane], x1 = feat[(size_t)n*128 + 64 + lane];
        float s = x0 + x1;
        #pragma unroll
        for (int off = 32; off > 0; off >>= 1) s += __shfl_xor(s, off);
        float mean = s * (1.f/128.f);
        float d0 = x0 - mean, d1 = x1 - mean;
        float s2 = d0*d0 + d1*d1;
        #pragma unroll
        for (int off = 32; off > 0; off >>= 1) s2 += __shfl_xor(s2, off);
        float rstd = rsqrtf(s2 * (1.f/128.f) + LNEPS);
        float y0 = d0*rstd*fg[lane] + fb[lane];
        float y1 = d1*rstd*fg[64+lane] + fb[64+lane];
        float s3 = y0*y0 + y1*y1;
        #pragma unroll
        for (int off = 32; off > 0; off >>= 1) s3 += __shfl_xor(s3, off);
        float rl2 = 1.f / fmaxf(sqrtf(s3), 1e-12f);
        float c0 = y0*rl2, c1 = y1*rl2;
        int g = gt[n];
        const float* uk = u + g*10;
        float bv = -1e30f; int idx = 0;
        #pragma unroll
        for (int m = 0; m < 10; ++m) {
            float pm = expv[(size_t)n*12 + m] * uk[m];
            if (pm > bv) { bv = pm; idx = m; }
        }
        float* frow = facc + (size_t)(g*10+idx)*128;
        atomicAdd(&frow[lane], c0);
        atomicAdd(&frow[64+lane], c1);
    }
}

// ---- momentum update + renormalize prototypes
__global__ __launch_bounds__(64) void k_proto_update(
    const float* __restrict__ facc, const float* __restrict__ ncount,
    const float* __restrict__ pn, float* __restrict__ outp)
{
    const float OMG = (float)(1.0 - 0.99);
    int j = blockIdx.x, l = threadIdx.x;
    float f0 = facc[(size_t)j*128+l], f1 = facc[(size_t)j*128+64+l];
    float ss = f0*f0 + f1*f1;
    #pragma unroll
    for (int off = 32; off > 0; off >>= 1) ss += __shfl_xor(ss, off);
    float fl2 = fmaxf(sqrtf(ss), 1e-12f);
    float fn0 = f0/fl2, fn1 = f1/fl2;
    float p0 = pn[(size_t)j*128+l], p1 = pn[(size_t)j*128+64+l];
    float u0 = 0.99f*p0 + OMG*fn0, u1 = 0.99f*p1 + OMG*fn1;
    bool ok = ncount[j] > 0.f;
    float s0 = ok ? u0 : p0, s1 = ok ? u1 : p1;
    float ss2 = s0*s0 + s1*s1;
    #pragma unroll
    for (int off = 32; off > 0; off >>= 1) ss2 += __shfl_xor(ss2, off);
    float l2 = fmaxf(sqrtf(ss2), 1e-12f);
    outp[(size_t)j*128+l]      = s0/l2;
    outp[(size_t)j*128+64+l]   = s1/l2;
}

extern "C" void kernel_launch(void* const* d_in, const int* in_sizes, int n_in,
                              void* d_out, int out_size, void* d_ws, size_t ws_size,
                              hipStream_t stream)
{
    const float* feat   = (const float*)d_in[0];
    const int*   gt     = (const int*)  d_in[1];
    const float* protos = (const float*)d_in[2];
    const float* fg     = (const float*)d_in[3];
    const float* fb     = (const float*)d_in[4];
    const float* mg     = (const float*)d_in[5];
    const float* mb     = (const float*)d_in[6];

    float* out      = (float*)d_out;
    float* out_seg  = out;
    float* plog     = out + (size_t)NPTS*20;
    float* ptarget  = out + (size_t)NPTS*220;
    float* newp     = out + (size_t)NPTS*221;

    float* ws   = (float*)d_ws;
    float* pn   = ws + WS_PN;
    _Float16* phi = (_Float16*)(ws + WS_PHI);
    _Float16* plo = (_Float16*)(ws + WS_PLO);
    float* facc = ws + WS_F;
    float* ncnt = ws + WS_NCOUNT;
    int*   ccnt = (int*)(ws + WS_CCNT);
    float* uh   = ws + WS_UH;
    float* sk   = ws + WS_SK;
    float* Bc   = ws + WS_BC;
    float* psb  = ws + WS_PSB;
    float* pr   = ws + WS_PR;
    float* expv = ws + WS_EXPV;
    float* corr = ws + WS_CORR;
    int*   cidx = (int*)(ws + WS_CIDX);

    // zero facc + ncount + ccnt (contiguous)
    hipMemsetAsync(facc, 0, (25600 + 200 + 8)*sizeof(float), stream);
    hipLaunchKernelGGL(k_norm_protos, dim3(208), dim3(64), 0, stream, protos, pn, phi, plo);
    hipLaunchKernelGGL(k_main, dim3(256), dim3(512), 0, stream,
                       feat, gt, phi, plo, fg, fb, mg, mb, out_seg, plog, expv, psb, corr,
                       cidx, ccnt);
    hipLaunchKernelGGL(k_reduce_sB, dim3(40), dim3(256), 0, stream, psb, sk, Bc);
    for (int it = 1; it <= 3; ++it) {
        hipLaunchKernelGGL(k_row, dim3(1024), dim3(256), 0, stream, it, gt, expv, uh, sk, Bc, pr);
        hipLaunchKernelGGL(k_reduce_u, dim3(200), dim3(256), 0, stream, it, pr, uh);
    }
    hipLaunchKernelGGL(k_assign, dim3(1024), dim3(256), 0, stream,
                       gt, expv, uh + 400, corr, ptarget, ncnt);
    hipLaunchKernelGGL(k_accum, dim3(256), dim3(256), 0, stream,
                       feat, gt, fg, fb, expv, uh + 400, cidx, ccnt, facc);
    hipLaunchKernelGGL(k_proto_update, dim3(200), dim3(64), 0, stream, facc, ncnt, pn, newp);
}